// Round 7
// baseline (195.409 us; speedup 1.0000x reference)
//
#include <hip/hip_runtime.h>

// PatchEncoder fused kernel, round 9 (resubmit — R6 bench was an infra
// failure: "MI355X container failed twice"; kernel audited memory-safe
// and deadlock-free, no signal to act on).
// out[b, (h/16)*32 + w/16, (h%16)*48 + (w%16)*3 + c]
//   = conv3x3_SAME(X)[b,h,w,c] + bias[c]
//     + pos_emb[(h/4)*128 + (w/4), (h%4)*12 + (w%4)*3 + c]
//
// History: R4 69us, R5 86us (no-LDS loses), R6 63.7us, R8 75.4us
// (occupancy 36->45% yet SLOWER: occupancy was not the constraint).
// Diagnosis: the block is a serial chain with 3 all-wave barriers, each
// draining vmcnt(0); all 4 waves park together at every step. More
// resident blocks = more parked waves.
//
// R9: each wave's working set is disjoint (thread r2 reads LDS rows
// 2r2..2r2+3 only), so waves get PRIVATE 2048-float LDS regions and run
// fully autonomously — zero __syncthreads:
//  - wave wv DMAs its own 10 rows (h0+8wv-1 .. +8) as 8 flat 16B DMAs
//    (stride-200 packing, R8's verified addressing; 16B chunks never
//    cross the 200-float row boundary since 200%4==0).
//  - per-wave s_waitcnt vmcnt(0) (not a barrier) -> fixups -> compute.
//  - out-stage reuses own region: WAR-safe (FMA data-deps force all
//    ds_read completions first); explicit lgkmcnt(0) before drain.
//  - drain: wave's 8 rows = half-patches of 4 consecutive np -> runs of
//    1536B contiguous, 6 dwordx4 stores/lane.
//  - LDS 4*2048*4B = 32KB exactly -> 5 blocks/CU, 20 free-running waves.
// Cost: 6 duplicated halo rows/block across waves (same-CU -> L2 hits).
// Out-stage patch stride 392 floats (granule 98 = 2 mod 8): write
// residues 2p+3(g&3) and read residues lane+2p both uniform over 8.

#define BATCH 32
#define IMH 512
#define IMW 512
#define RSF 200            // input row stride, floats
#define WREG 2048          // per-wave LDS region, floats (8 DMAs * 256)
#define OPST 392           // out-stage patch stride, floats
#define TILEW 64
#define TILEH 32

__device__ __forceinline__ void dma16(const float* g, float* l) {
    __builtin_amdgcn_global_load_lds(
        (const __attribute__((address_space(1))) void*)g,
        (__attribute__((address_space(3))) void*)l,
        16, 0, 0);
}

__global__ __launch_bounds__(256, 5) void patch_enc_kernel(
    const float* __restrict__ X,     // [B,H,W,3] NHWC
    const float* __restrict__ Kw,    // [3,3,3,3] HWIO
    const float* __restrict__ bias,  // [3]
    const float* __restrict__ pos,   // [16384,48]
    float* __restrict__ out)         // [B,1024,768]
{
    __shared__ float lds[4 * WREG];   // 32 KB exactly -> 5 blocks/CU

    const int tid  = threadIdx.x;
    const int lane = tid & 63;
    const int wv   = tid >> 6;
    const int w0   = blockIdx.x * TILEW;
    const int h0   = blockIdx.y * TILEH;
    const int b    = blockIdx.z;

    const bool lEdge = (w0 == 0);
    const bool rEdge = (w0 == IMW - TILEW);
    const bool tEdge = (h0 == 0);
    const bool bEdge = (h0 == IMH - TILEH);
    const bool edge  = lEdge | rEdge | tEdge | bEdge;

    float* wlds = &lds[wv * WREG];
    const float* Xb = X + (size_t)b * (IMH * IMW * 3);

    // weights/bias first: SMEM s_loads (lgkmcnt), unaffected by vmcnt wait
    float wk[81];
#pragma unroll
    for (int i = 0; i < 81; ++i) wk[i] = Kw[i];
    const float bs0 = bias[0], bs1 = bias[1], bs2 = bias[2];

    // ---- per-wave async stage: 8 flat 16B DMAs fill [10 rows][200] ----
    // region float f <-> row f/200, o = f%200; o <-> global col 3*w0-4+o
    {
        const float* xlo = X;
        const float* xhi = X + (size_t)BATCH * IMH * IMW * 3 - 4;  // last 16B start
        const float* Xt  = Xb + (long)(h0 + 8 * wv - 1) * (IMW * 3) + (3 * w0 - 4);
#pragma unroll
        for (int d = 0; d < 8; ++d) {
            const int f   = 256 * d + 4 * lane;
            const int row = f / 200;                // const-divisor magic-mul
            const int o   = f - 200 * row;
            const float* gp = Xt + row * (IMW * 3) + o;
            if (edge) {                             // block-uniform; per-lane clamp
                gp = (gp < xlo) ? xlo : gp;
                gp = (gp > xhi) ? xhi : gp;
            }
            dma16(gp, &wlds[256 * d]);
        }
    }

    // wave-level wait: MY 8 DMAs landed (other waves keep running)
    asm volatile("s_waitcnt vmcnt(0)" ::: "memory");
    __builtin_amdgcn_sched_barrier(0);

    // ---- wave-local zero-pad fixups (edge blocks only) ----
    if (edge) {
        if (tEdge && wv == 0) for (int j = lane; j < RSF; j += 64) wlds[j] = 0.0f;            // h=-1
        if (bEdge && wv == 3) for (int j = lane; j < RSF; j += 64) wlds[9 * RSF + j] = 0.0f;  // h=512
        if (lEdge && lane < 10) {
            float* p = &wlds[lane * RSF];
            p[1] = 0.0f; p[2] = 0.0f; p[3] = 0.0f;            // col w=-1
        }
        if (rEdge && lane < 10) {
            float* p = &wlds[lane * RSF + 196];
            p[0] = 0.0f; p[1] = 0.0f; p[2] = 0.0f;            // col w=512
        }
    }

    // ---- compute: lane -> rows {h0+8wv+2r2, +1}, col group g (4 px) ----
    const int g  = lane & 15;
    const int r2 = lane >> 4;       // 0..3 within wave

    float acc0[12], acc1[12];
#pragma unroll
    for (int i = 0; i < 12; ++i) { acc0[i] = 0.0f; acc1[i] = 0.0f; }

    // region row (2*r2+q): feeds out-row0 with weight-row q (q<=2),
    // out-row1 with weight-row q-1 (q>=1). 4 rows read for 2 computed.
#pragma unroll
    for (int q = 0; q < 4; ++q) {
        const float* bp = &wlds[(2 * r2 + q) * RSF + 12 * g];
        float s[20];
#pragma unroll
        for (int j = 0; j < 5; ++j)
            *(float4*)&s[4 * j] = *(const float4*)(bp + 4 * j);   // ds_read_b128
#pragma unroll
        for (int dc = 0; dc < 3; ++dc)
#pragma unroll
        for (int ci = 0; ci < 3; ++ci) {
#pragma unroll
            for (int i = 0; i < 4; ++i) {
                const float x = s[3 * (i + dc) + ci + 1];
                if (q <= 2) {
                    const float* wp = &wk[((q * 3 + dc) * 3 + ci) * 3];
                    acc0[i * 3 + 0] = fmaf(x, wp[0], acc0[i * 3 + 0]);
                    acc0[i * 3 + 1] = fmaf(x, wp[1], acc0[i * 3 + 1]);
                    acc0[i * 3 + 2] = fmaf(x, wp[2], acc0[i * 3 + 2]);
                }
                if (q >= 1) {
                    const float* wp = &wk[(((q - 1) * 3 + dc) * 3 + ci) * 3];
                    acc1[i * 3 + 0] = fmaf(x, wp[0], acc1[i * 3 + 0]);
                    acc1[i * 3 + 1] = fmaf(x, wp[1], acc1[i * 3 + 1]);
                    acc1[i * 3 + 2] = fmaf(x, wp[2], acc1[i * 3 + 2]);
                }
            }
        }
    }

    // ---- bias + pos_emb (adjacent rows share n: one 96B load) ----
    const int hg0 = h0 + 8 * wv + 2 * r2;
    const int wg0 = w0 + 4 * g;
    const int n   = (hg0 >> 2) * 128 + (wg0 >> 2);
    const float* pp = pos + (size_t)n * 48 + (hg0 & 3) * 12;   // 16B aligned
    float pr[24];
#pragma unroll
    for (int j = 0; j < 6; ++j)
        *(float4*)&pr[4 * j] = *(const float4*)(pp + 4 * j);

    float v0[12], v1[12];
#pragma unroll
    for (int k = 0; k < 12; ++k) {
        const float bsk = (k % 3 == 0) ? bs0 : (k % 3 == 1) ? bs1 : bs2;
        v0[k] = acc0[k] + bsk + pr[k];
        v1[k] = acc1[k] + bsk + pr[12 + k];
    }

    // ---- out-stage into OWN region (reuse; WAR-safe: FMA deps already
    // forced all ds_read completions). Layout [patch4][8 rows][48]. ----
    {
        const int p  = g >> 2;                                // local patch 0..3
        const int o0 = p * OPST + (2 * r2) * 48 + (g & 3) * 12;
        *(float4*)&wlds[o0 + 0] = make_float4(v0[0], v0[1], v0[2],  v0[3]);
        *(float4*)&wlds[o0 + 4] = make_float4(v0[4], v0[5], v0[6],  v0[7]);
        *(float4*)&wlds[o0 + 8] = make_float4(v0[8], v0[9], v0[10], v0[11]);
        const int o1 = o0 + 48;                               // row+1
        *(float4*)&wlds[o1 + 0] = make_float4(v1[0], v1[1], v1[2],  v1[3]);
        *(float4*)&wlds[o1 + 4] = make_float4(v1[4], v1[5], v1[6],  v1[7]);
        *(float4*)&wlds[o1 + 8] = make_float4(v1[8], v1[9], v1[10], v1[11]);
    }
    asm volatile("s_waitcnt lgkmcnt(0)" ::: "memory");   // writes landed
    __builtin_amdgcn_sched_barrier(0);

    // ---- drain: wave's 8 rows = half-patches of np0..np0+3 ----
    // run of 384 floats (1536B) contiguous per patch-half
    {
        float* outw = out + (size_t)b * 786432
                    + (size_t)((h0 >> 4) * 32 + (w0 >> 4) + (wv >> 1) * 32) * 768
                    + (wv & 1) * 384;
#pragma unroll
        for (int c = 0; c < 6; ++c) {
            const int fl  = 4 * lane + 256 * c;     // 0..1535
            const int p   = fl / 384;               // exact const-div
            const int rem = fl - 384 * p;
            const float4 val = *(const float4*)&wlds[p * OPST + rem];
            *(float4*)(outw + p * 768 + rem) = val;
        }
    }
}

extern "C" void kernel_launch(void* const* d_in, const int* in_sizes, int n_in,
                              void* d_out, int out_size, void* d_ws, size_t ws_size,
                              hipStream_t stream) {
    const float* X    = (const float*)d_in[0];
    const float* Kw   = (const float*)d_in[1];
    const float* bias = (const float*)d_in[2];
    const float* pos  = (const float*)d_in[3];
    float* out = (float*)d_out;

    dim3 grid(IMW / TILEW, IMH / TILEH, BATCH);   // 8 x 16 x 32 = 4096 blocks
    patch_enc_kernel<<<grid, 256, 0, stream>>>(X, Kw, bias, pos, out);
}